// Round 5
// baseline (969.436 us; speedup 1.0000x reference)
//
#include <hip/hip_runtime.h>
#include <math.h>

#define NB   8
#define NPTS 4096
#define MPER 1024
#define MTOT (NB*MPER)
#define CIN  64
#define KNN  64
#define CAP  512
// (0.2*0.2) computed in double, as the reference's python-float R*R
#define R2D  0.04000000000000001

typedef unsigned int u32;
typedef unsigned long long u64;
typedef float v2f __attribute__((ext_vector_type(2)));
using s16x8 = __attribute__((ext_vector_type(8))) short;   // 8 bf16 (4 VGPRs)
using f32x4 = __attribute__((ext_vector_type(4))) float;

// exact IEEE fp32 distance, reference order: ((dx*dx + dy*dy) + dz*dz), no FMA
__device__ __forceinline__ float d2f(float ax, float ay, float az,
                                     float bx, float by, float bz) {
    float dx = __fsub_rn(ax, bx);
    float dy = __fsub_rn(ay, by);
    float dz = __fsub_rn(az, bz);
    return __fadd_rn(__fadd_rn(__fmul_rn(dx, dx), __fmul_rn(dy, dy)),
                     __fmul_rn(dz, dz));
}

// CDNA packed 2xFP32 ops — IEEE-identical per component; asm, so never contracted
__device__ __forceinline__ v2f pk_add(v2f a, v2f b) {
    v2f d;
    asm("v_pk_add_f32 %0, %1, %2" : "=v"(d) : "v"(a), "v"(b));
    return d;
}
__device__ __forceinline__ v2f pk_mul(v2f a, v2f b) {
    v2f d;
    asm("v_pk_mul_f32 %0, %1, %2" : "=v"(d) : "v"(a), "v"(b));
    return d;
}

// float -> bf16 bits, round-to-nearest-even (finite inputs only)
__device__ __forceinline__ unsigned short f2bf(float f) {
    u32 x = __float_as_uint(f);
    u32 r = (x + 0x7fffu + ((x >> 16) & 1u)) >> 16;
    return (unsigned short)r;
}
__device__ __forceinline__ u32 pk2(float a, float b) {
    return (u32)f2bf(a) | ((u32)f2bf(b) << 16);
}

__device__ __forceinline__ f32x4 mfma16(s16x8 a, s16x8 b, f32x4 c) {
    return __builtin_amdgcn_mfma_f32_16x16x32_bf16(a, b, c, 0, 0, 0);
}

// full-wave (64-lane) max reduction of a u64 key via DPP; result valid in lane 63.
__device__ __forceinline__ unsigned long long wave_max_u64_dpp(unsigned long long key)
{
#define DPPMAX(ctrl, rmask) do {                                                   \
        unsigned int lo_ = (unsigned int)key;                                      \
        unsigned int hi_ = (unsigned int)(key >> 32);                              \
        unsigned int plo = (unsigned int)__builtin_amdgcn_update_dpp(              \
            0, (int)lo_, ctrl, rmask, 0xf, false);                                 \
        unsigned int phi = (unsigned int)__builtin_amdgcn_update_dpp(              \
            0, (int)hi_, ctrl, rmask, 0xf, false);                                 \
        unsigned long long pk = ((unsigned long long)phi << 32) | plo;             \
        if (pk > key) key = pk;                                                    \
    } while (0)
    DPPMAX(0x111, 0xf);   // row_shr:1
    DPPMAX(0x112, 0xf);   // row_shr:2
    DPPMAX(0x114, 0xf);   // row_shr:4
    DPPMAX(0x118, 0xf);   // row_shr:8
    DPPMAX(0x142, 0xa);   // row_bcast:15 -> rows 1,3
    DPPMAX(0x143, 0xc);   // row_bcast:31 -> rows 2,3
#undef DPPMAX
    return key;
}

// ---------------- Kernel 1: farthest point sampling ----------------
// one block per cloud; 256 threads (4 waves), 16 points/thread (8 packed pairs).
// Per iteration: packed distance/min update -> local argmax -> DPP wave argmax
// -> lane63 posts (key | iter-tag) to parity mailbox -> all waves spin-read the
// 4 slots (no s_barrier) -> redundant 4-way select -> broadcast coord fetch.
// Key layout: hi32 = d2 float bits (>=0), lo32 = (tag<<12) | (4095 - idx);
// tag is wave-uniform so lexicographic (d2, smaller-idx-wins) order is kept.
__global__ __launch_bounds__(256) void fps_kernel(const float* __restrict__ pos,
                                                  int* __restrict__ sel)
{
    const int b    = blockIdx.x;
    const int t    = threadIdx.x;
    const int lane = t & 63;
    const int wv   = t >> 6;
    const float* pb = pos + (size_t)b * NPTS * 3;

    __shared__ float lx[NPTS], ly[NPTS], lz[NPTS];
    __shared__ u64 skey[2][4];

    v2f px[8], py[8], pz[8], mind[8];
#pragma unroll
    for (int pr = 0; pr < 8; ++pr) {
        int j0 = (2 * pr + 0) * 256 + t;
        int j1 = (2 * pr + 1) * 256 + t;
        float x0 = pb[j0 * 3 + 0], y0 = pb[j0 * 3 + 1], z0 = pb[j0 * 3 + 2];
        float x1 = pb[j1 * 3 + 0], y1 = pb[j1 * 3 + 1], z1 = pb[j1 * 3 + 2];
        px[pr] = v2f{x0, x1}; py[pr] = v2f{y0, y1}; pz[pr] = v2f{z0, z1};
        mind[pr] = v2f{3.0e38f, 3.0e38f};   // first fmin yields exactly d2-to-p0
        lx[j0] = x0; ly[j0] = y0; lz[j0] = z0;
        lx[j1] = x1; ly[j1] = y1; lz[j1] = z1;
    }
    if (t < 8) ((volatile u64*)&skey[0][0])[t] = 0ull;   // tag 0 != first tag 1
    if (t == 0) sel[b * MPER + 0] = b * NPTS + 0;
    __syncthreads();   // staging + mailbox init visible to all waves

    float cx = lx[0], cy = ly[0], cz = lz[0];
    volatile u64* vk = &skey[0][0];

    for (int it = 1; it < MPER; ++it) {
        const v2f ncx = v2f{-cx, -cx};
        const v2f ncy = v2f{-cy, -cy};
        const v2f ncz = v2f{-cz, -cz};

        float bv = -1.0f; int bi = 0;
#pragma unroll
        for (int pr = 0; pr < 8; ++pr) {
            v2f dx = pk_add(px[pr], ncx);          // p + (-c) == p - c exactly
            v2f dy = pk_add(py[pr], ncy);
            v2f dz = pk_add(pz[pr], ncz);
            v2f s  = pk_add(pk_mul(dx, dx), pk_mul(dy, dy));
            v2f d2 = pk_add(s, pk_mul(dz, dz));    // ((dx^2+dy^2)+dz^2), exact order
            float m0 = fminf(mind[pr].x, d2.x);
            float m1 = fminf(mind[pr].y, d2.y);
            mind[pr].x = m0; mind[pr].y = m1;
            if (m0 > bv) { bv = m0; bi = (2 * pr + 0) * 256 + t; }
            if (m1 > bv) { bv = m1; bi = (2 * pr + 1) * 256 + t; }
        }

        const u32 tag = (u32)it & 255u;
        u64 key = ((u64)__float_as_uint(bv) << 32)
                | (u64)((tag << 12) | (u32)(4095 - bi));
        key = wave_max_u64_dpp(key);

        const int p = it & 1;
        if (lane == 63) *((volatile u64*)&skey[p][wv]) = key;

        // spin until all 4 slots of this parity carry the current tag
        u64 q0, q1, q2, q3;
        for (;;) {
            q0 = vk[p * 4 + 0]; q1 = vk[p * 4 + 1];
            q2 = vk[p * 4 + 2]; q3 = vk[p * 4 + 3];
            if (((((u32)q0 >> 12) & 255u) == tag) &&
                ((((u32)q1 >> 12) & 255u) == tag) &&
                ((((u32)q2 >> 12) & 255u) == tag) &&
                ((((u32)q3 >> 12) & 255u) == tag)) break;
        }

        u64 ka = q0 > q1 ? q0 : q1;
        u64 kb = q2 > q3 ? q2 : q3;
        u64 km = ka > kb ? ka : kb;
        int pick = 4095 - (int)((u32)km & 0xFFFu);

        cx = lx[pick]; cy = ly[pick]; cz = lz[pick];
        if (t == 0) sel[b * MPER + it] = b * NPTS + pick;
    }
}

// ---------------- Kernel 2: ball query + K nearest (rank select) ----------------
__global__ __launch_bounds__(256) void ballq_kernel(
    const float* __restrict__ pos, const int* __restrict__ sel,
    int* __restrict__ nbr, int* __restrict__ cnt,
    float* __restrict__ out_pos, float* __restrict__ out_batch)
{
    __shared__ float cd[4][CAP];
    __shared__ int   ci[4][CAP];

    const int wv   = threadIdx.x >> 6;
    const int lane = threadIdx.x & 63;
    const int c    = blockIdx.x * 4 + wv;
    const int sg   = sel[c];
    const int b    = c >> 10;            // c / MPER
    const int base = b * NPTS;
    const float* pb = pos + (size_t)base * 3;
    const float qx = pos[(size_t)sg * 3 + 0];
    const float qy = pos[(size_t)sg * 3 + 1];
    const float qz = pos[(size_t)sg * 3 + 2];

    int n = 0;
    for (int r0 = 0; r0 < NPTS; r0 += 64) {
        const int j = r0 + lane;
        float x = pb[j * 3 + 0], y = pb[j * 3 + 1], z = pb[j * 3 + 2];
        float d2 = d2f(x, y, z, qx, qy, qz);
        bool inside = ((double)d2 <= R2D);
        unsigned long long m = __ballot(inside);
        if (inside) {
            int myoff = n + __popcll(m & ((1ull << lane) - 1ull));
            if (myoff < CAP) { cd[wv][myoff] = d2; ci[wv][myoff] = j; }
        }
        n += __popcll(m);
    }
    n = min(n, CAP);
    __syncthreads();

    for (int i = lane; i < n; i += 64) {
        float d = cd[wv][i]; int id = ci[wv][i];
        int rank = 0;
        for (int j = 0; j < n; ++j) {
            float dj = cd[wv][j]; int ij = ci[wv][j];
            rank += (dj < d || (dj == d && ij < id)) ? 1 : 0;
        }
        if (rank < KNN) nbr[(size_t)c * KNN + rank] = base + id;
    }
    if (lane == 0) {
        cnt[c] = min(n, KNN);
        out_pos[c * 3 + 0] = qx;
        out_pos[c * 3 + 1] = qy;
        out_pos[c * 3 + 2] = qz;
        out_batch[c] = (float)b;
    }
}

// ---------------- weight prep: bf16 transposed+padded weights into ws ----------
// ws layout (ushort units): W1t[64][104] | W2t[64][72] | W3t[128][72]
#define W1T_U 6656
#define W2T_U 4608
#define W3T_U 9216
#define WTOT_U 20480

__global__ __launch_bounds__(256) void prep_weights(
    const float* __restrict__ W1, const float* __restrict__ W2,
    const float* __restrict__ W3, unsigned short* __restrict__ wsW)
{
    int i = blockIdx.x * 256 + threadIdx.x;
    if (i >= WTOT_U) return;
    float v;
    if (i < W1T_U) {
        int cr = i / 104, k = i - cr * 104;
        v = (k < 67) ? W1[k * 64 + cr] : 0.0f;
    } else if (i < W1T_U + W2T_U) {
        int j = i - W1T_U;
        int cr = j / 72, k = j - cr * 72;
        v = (k < 64) ? W2[k * 64 + cr] : 0.0f;
    } else {
        int j = i - (W1T_U + W2T_U);
        int cr = j / 72, k = j - cr * 72;
        v = (k < 64) ? W3[k * 128 + cr] : 0.0f;
    }
    wsW[i] = f2bf(v);
}

// ---------------- Kernel 3: gather + MFMA MLP + masked max ---------------------
__global__ __launch_bounds__(256) void mlp_kernel(
    const float* __restrict__ x, const float* __restrict__ pos,
    const int* __restrict__ nbr, const int* __restrict__ cnt,
    const float* __restrict__ out_pos,
    const unsigned short* __restrict__ wsW,
    const float* __restrict__ b1, const float* __restrict__ b2,
    const float* __restrict__ b3,
    float* __restrict__ out_x)
{
    __shared__ __align__(16) unsigned short smA[6656];   // A1[64][104]; later H2[64][72]; later f32 partial[4][128]
    __shared__ __align__(16) unsigned short smW[WTOT_U]; // W1t (later H1[64][72]) | W2t | W3t

    const int c = blockIdx.x;
    const int t = threadIdx.x;
    const int n = cnt[c];

    // ---- stage weights ws -> LDS (linear, 40960 B) ----
    {
        const uint4* src = (const uint4*)wsW;
        uint4* dst = (uint4*)smW;
#pragma unroll
        for (int i = 0; i < 10; ++i) dst[t + 256 * i] = src[t + 256 * i];
    }

    // ---- stage A1: row k = [bf16(x[nb][0..64)), bf16(pos[nb]-q), zeros] ----
    {
        const int k = t >> 2, g = t & 3;
        const bool valid = k < n;
        const int nb = valid ? nbr[(size_t)c * KNN + k] : 0;
        const float* xr = x + (size_t)nb * CIN + g * 16;
        float4 f0, f1, f2, f3;
        if (valid) {
            f0 = *(const float4*)(xr + 0);
            f1 = *(const float4*)(xr + 4);
            f2 = *(const float4*)(xr + 8);
            f3 = *(const float4*)(xr + 12);
        } else {
            f0 = float4{0.f, 0.f, 0.f, 0.f};
            f1 = f0; f2 = f0; f3 = f0;
        }
        uint4 ua = { pk2(f0.x, f0.y), pk2(f0.z, f0.w), pk2(f1.x, f1.y), pk2(f1.z, f1.w) };
        uint4 ub = { pk2(f2.x, f2.y), pk2(f2.z, f2.w), pk2(f3.x, f3.y), pk2(f3.z, f3.w) };
        *(uint4*)&smA[k * 104 + g * 16 + 0] = ua;
        *(uint4*)&smA[k * 104 + g * 16 + 8] = ub;
        if (g == 0) {
            float r0 = 0.f, r1 = 0.f, r2 = 0.f;
            if (valid) {
                float q0 = out_pos[c * 3 + 0];
                float q1 = out_pos[c * 3 + 1];
                float q2 = out_pos[c * 3 + 2];
                r0 = __fsub_rn(pos[(size_t)nb * 3 + 0], q0);
                r1 = __fsub_rn(pos[(size_t)nb * 3 + 1], q1);
                r2 = __fsub_rn(pos[(size_t)nb * 3 + 2], q2);
            }
            uint4 uz = { 0u, 0u, 0u, 0u };
            uint4 ur = { pk2(r0, r1), (u32)f2bf(r2), 0u, 0u };
            *(uint4*)&smA[k * 104 + 64] = ur;
            *(uint4*)&smA[k * 104 + 72] = uz;
            *(uint4*)&smA[k * 104 + 80] = uz;
            *(uint4*)&smA[k * 104 + 88] = uz;
            *(uint4*)&smA[k * 104 + 96] = uz;
        }
    }
    __syncthreads();

    const int l  = t & 63;
    const int w  = t >> 6;
    const int lr = l & 15;
    const int kg = l >> 4;

    float bias1[4], bias2[4];
#pragma unroll
    for (int nt = 0; nt < 4; ++nt) {
        bias1[nt] = b1[nt * 16 + lr];
        bias2[nt] = b2[nt * 16 + lr];
    }

    const unsigned short* W1t = smW;                    // stride 104
    const unsigned short* W2t = smW + W1T_U;            // stride 72
    const unsigned short* W3t = smW + W1T_U + W2T_U;    // stride 72
    unsigned short* H1 = smW;                           // [64][72] overlays W1t
    unsigned short* H2 = smA;                           // [64][72] overlays A1

    // ---- layer 1: A1[64][96+] x W1t -> H1 (relu) ----
    f32x4 acc1[4];
#pragma unroll
    for (int nt = 0; nt < 4; ++nt) acc1[nt] = f32x4{0.f, 0.f, 0.f, 0.f};
    {
        const int ao = (w * 16 + lr) * 104 + kg * 8;
        const int bo = lr * 104 + kg * 8;
#pragma unroll
        for (int kc = 0; kc < 3; ++kc) {
            s16x8 af = *(const s16x8*)&smA[ao + kc * 32];
#pragma unroll
            for (int nt = 0; nt < 4; ++nt) {
                s16x8 bf = *(const s16x8*)&W1t[bo + nt * 1664 + kc * 32];
                acc1[nt] = mfma16(af, bf, acc1[nt]);
            }
        }
    }
    __syncthreads();   // all W1t/A1 reads complete before overlaying W1t with H1
#pragma unroll
    for (int nt = 0; nt < 4; ++nt) {
        const int col = nt * 16 + lr;
#pragma unroll
        for (int r = 0; r < 4; ++r) {
            const int row = w * 16 + kg * 4 + r;
            float v = fmaxf(acc1[nt][r] + bias1[nt], 0.0f);
            H1[row * 72 + col] = f2bf(v);
        }
    }
    __syncthreads();

    // ---- layer 2: H1 x W2t -> H2 (relu) ----
    f32x4 acc2[4];
#pragma unroll
    for (int nt = 0; nt < 4; ++nt) acc2[nt] = f32x4{0.f, 0.f, 0.f, 0.f};
    {
        const int ao = (w * 16 + lr) * 72 + kg * 8;
        const int bo = lr * 72 + kg * 8;
#pragma unroll
        for (int kc = 0; kc < 2; ++kc) {
            s16x8 af = *(const s16x8*)&H1[ao + kc * 32];
#pragma unroll
            for (int nt = 0; nt < 4; ++nt) {
                s16x8 bf = *(const s16x8*)&W2t[bo + nt * 1152 + kc * 32];
                acc2[nt] = mfma16(af, bf, acc2[nt]);
            }
        }
    }
    // H2 overlays A1 (dead since layer-1 barrier); disjoint from H1/W2t.
#pragma unroll
    for (int nt = 0; nt < 4; ++nt) {
        const int col = nt * 16 + lr;
#pragma unroll
        for (int r = 0; r < 4; ++r) {
            const int row = w * 16 + kg * 4 + r;
            float v = fmaxf(acc2[nt][r] + bias2[nt], 0.0f);
            H2[row * 72 + col] = f2bf(v);
        }
    }
    __syncthreads();

    // ---- layer 3: H2 x W3t -> acc3 (64x128 per block) ----
    f32x4 acc3[8];
#pragma unroll
    for (int nt = 0; nt < 8; ++nt) acc3[nt] = f32x4{0.f, 0.f, 0.f, 0.f};
    {
        const int ao = (w * 16 + lr) * 72 + kg * 8;
        const int bo = lr * 72 + kg * 8;
#pragma unroll
        for (int kc = 0; kc < 2; ++kc) {
            s16x8 af = *(const s16x8*)&H2[ao + kc * 32];
#pragma unroll
            for (int nt = 0; nt < 8; ++nt) {
                s16x8 bf = *(const s16x8*)&W3t[bo + nt * 1152 + kc * 32];
                acc3[nt] = mfma16(af, bf, acc3[nt]);
            }
        }
    }

    // ---- masked max over valid rows; bias added after max (column-constant) ----
    float pm[8];
#pragma unroll
    for (int nt = 0; nt < 8; ++nt) pm[nt] = -1e30f;
#pragma unroll
    for (int r = 0; r < 4; ++r) {
        const int row = w * 16 + kg * 4 + r;
        if (row < n) {
#pragma unroll
            for (int nt = 0; nt < 8; ++nt) pm[nt] = fmaxf(pm[nt], acc3[nt][r]);
        }
    }
#pragma unroll
    for (int nt = 0; nt < 8; ++nt) {
        pm[nt] = fmaxf(pm[nt], __shfl_xor(pm[nt], 16));
        pm[nt] = fmaxf(pm[nt], __shfl_xor(pm[nt], 32));
    }
    __syncthreads();   // all layer-3 LDS reads done; reuse smA as f32 partials
    float* pbuf = (float*)smA;            // [4][128]
    if (kg == 0) {
#pragma unroll
        for (int nt = 0; nt < 8; ++nt) pbuf[w * 128 + nt * 16 + lr] = pm[nt];
    }
    __syncthreads();
    if (t < 128) {
        float m = fmaxf(fmaxf(pbuf[t], pbuf[128 + t]),
                        fmaxf(pbuf[256 + t], pbuf[384 + t]));
        out_x[(size_t)c * 128 + t] = m + b3[t];
    }
}

extern "C" void kernel_launch(void* const* d_in, const int* in_sizes, int n_in,
                              void* d_out, int out_size, void* d_ws, size_t ws_size,
                              hipStream_t stream)
{
    const float* x   = (const float*)d_in[0];
    const float* pos = (const float*)d_in[1];
    const float* W1 = (const float*)d_in[3];
    const float* b1 = (const float*)d_in[4];
    const float* W2 = (const float*)d_in[5];
    const float* b2 = (const float*)d_in[6];
    const float* W3 = (const float*)d_in[7];
    const float* b3 = (const float*)d_in[8];

    float* out_x     = (float*)d_out;                    // [8192,128]
    float* out_pos   = out_x + (size_t)MTOT * 128;       // [8192,3]
    float* out_batch = out_pos + (size_t)MTOT * 3;       // [8192]

    int* sel = (int*)d_ws;                               // [8192]
    int* nbr = sel + MTOT;                               // [8192*64]
    int* cnt = nbr + (size_t)MTOT * KNN;                 // [8192]
    unsigned short* wsW = (unsigned short*)(cnt + MTOT); // [20480] bf16 weights

    prep_weights<<<(WTOT_U + 255) / 256, 256, 0, stream>>>(W1, W2, W3, wsW);
    fps_kernel<<<NB, 256, 0, stream>>>(pos, sel);
    ballq_kernel<<<MTOT / 4, 256, 0, stream>>>(pos, sel, nbr, cnt, out_pos, out_batch);
    mlp_kernel<<<MTOT, 256, 0, stream>>>(x, pos, nbr, cnt, out_pos, wsW,
                                         b1, b2, b3, out_x);
}

// Round 6
// 894.067 us; speedup vs baseline: 1.0843x; 1.0843x over previous
//
#include <hip/hip_runtime.h>
#include <math.h>

#define NB   8
#define NPTS 4096
#define MPER 1024
#define MTOT (NB*MPER)
#define CIN  64
#define KNN  64
#define CAP  512
// (0.2*0.2) computed in double, as the reference's python-float R*R
#define R2D  0.04000000000000001

typedef unsigned int u32;
typedef unsigned long long u64;
typedef float v2f __attribute__((ext_vector_type(2)));
using s16x8 = __attribute__((ext_vector_type(8))) short;   // 8 bf16 (4 VGPRs)
using f32x4 = __attribute__((ext_vector_type(4))) float;

// exact IEEE fp32 distance, reference order: ((dx*dx + dy*dy) + dz*dz), no FMA
__device__ __forceinline__ float d2f(float ax, float ay, float az,
                                     float bx, float by, float bz) {
    float dx = __fsub_rn(ax, bx);
    float dy = __fsub_rn(ay, by);
    float dz = __fsub_rn(az, bz);
    return __fadd_rn(__fadd_rn(__fmul_rn(dx, dx), __fmul_rn(dy, dy)),
                     __fmul_rn(dz, dz));
}

// CDNA packed 2xFP32 ops — IEEE-identical per component; asm, never contracted.
// (bit-exactness HW-verified in rounds 3/5: FPS picks matched reference exactly)
__device__ __forceinline__ v2f pk_add(v2f a, v2f b) {
    v2f d;
    asm("v_pk_add_f32 %0, %1, %2" : "=v"(d) : "v"(a), "v"(b));
    return d;
}
__device__ __forceinline__ v2f pk_mul(v2f a, v2f b) {
    v2f d;
    asm("v_pk_mul_f32 %0, %1, %2" : "=v"(d) : "v"(a), "v"(b));
    return d;
}

// float -> bf16 bits, round-to-nearest-even (finite inputs only)
__device__ __forceinline__ unsigned short f2bf(float f) {
    u32 x = __float_as_uint(f);
    u32 r = (x + 0x7fffu + ((x >> 16) & 1u)) >> 16;
    return (unsigned short)r;
}
__device__ __forceinline__ u32 pk2(float a, float b) {
    return (u32)f2bf(a) | ((u32)f2bf(b) << 16);
}

__device__ __forceinline__ f32x4 mfma16(s16x8 a, s16x8 b, f32x4 c) {
    return __builtin_amdgcn_mfma_f32_16x16x32_bf16(a, b, c, 0, 0, 0);
}

// full-wave (64-lane) max reduction of a u64 key via DPP; result valid in lane 63.
__device__ __forceinline__ u64 wave_max_u64_dpp(u64 key)
{
#define DPPMAX(ctrl, rmask) do {                                                   \
        u32 lo_ = (u32)key;                                                        \
        u32 hi_ = (u32)(key >> 32);                                                \
        u32 plo = (u32)__builtin_amdgcn_update_dpp(                                \
            0, (int)lo_, ctrl, rmask, 0xf, false);                                 \
        u32 phi = (u32)__builtin_amdgcn_update_dpp(                                \
            0, (int)hi_, ctrl, rmask, 0xf, false);                                 \
        u64 pk = ((u64)phi << 32) | plo;                                           \
        if (pk > key) key = pk;                                                    \
    } while (0)
    DPPMAX(0x111, 0xf);   // row_shr:1
    DPPMAX(0x112, 0xf);   // row_shr:2
    DPPMAX(0x114, 0xf);   // row_shr:4
    DPPMAX(0x118, 0xf);   // row_shr:8
    DPPMAX(0x142, 0xa);   // row_bcast:15 -> rows 1,3
    DPPMAX(0x143, 0xc);   // row_bcast:31 -> rows 2,3
#undef DPPMAX
    return key;
}

// mailbox entry: wave winner's key + coordinates (32B aligned)
struct __align__(16) MB { u64 key; float x, y, z; u32 pad; };

// ---------------- Kernel 1: farthest point sampling ----------------
// one block per cloud; 256 threads (4 waves), 16 pts/thread (8 packed pairs).
// Per iteration: pk distance/min update + local argmax -> speculative per-lane
// coord gather (latency hidden under DPP) -> u64 DPP wave argmax -> readlane
// broadcast -> unique winner lane writes {key,x,y,z} to parity mailbox ->
// s_barrier -> all threads read 4 entries, 3-round cndmask tournament.
__global__ __launch_bounds__(256) void fps_kernel(const float* __restrict__ pos,
                                                  int* __restrict__ sel)
{
    const int b  = blockIdx.x;
    const int t  = threadIdx.x;
    const int wv = t >> 6;
    const float* pb = pos + (size_t)b * NPTS * 3;

    __shared__ float lx[NPTS], ly[NPTS], lz[NPTS];
    __shared__ MB mbox[2][4];

    v2f px[8], py[8], pz[8], mind[8];
#pragma unroll
    for (int pr = 0; pr < 8; ++pr) {
        int j0 = (2 * pr + 0) * 256 + t;
        int j1 = (2 * pr + 1) * 256 + t;
        float x0 = pb[j0 * 3 + 0], y0 = pb[j0 * 3 + 1], z0 = pb[j0 * 3 + 2];
        float x1 = pb[j1 * 3 + 0], y1 = pb[j1 * 3 + 1], z1 = pb[j1 * 3 + 2];
        px[pr] = v2f{x0, x1}; py[pr] = v2f{y0, y1}; pz[pr] = v2f{z0, z1};
        mind[pr] = v2f{3.0e38f, 3.0e38f};   // first fmin yields exactly d2-to-p0
        lx[j0] = x0; ly[j0] = y0; lz[j0] = z0;
        lx[j1] = x1; ly[j1] = y1; lz[j1] = z1;
    }
    if (t == 0) sel[b * MPER + 0] = b * NPTS + 0;
    __syncthreads();

    float cx = lx[0], cy = ly[0], cz = lz[0];

    for (int it = 1; it < MPER; ++it) {
        const v2f ncx = v2f{-cx, -cx};
        const v2f ncy = v2f{-cy, -cy};
        const v2f ncz = v2f{-cz, -cz};

        // local argmax of updated min-dists (ascending j + strict > keeps the
        // lowest index on ties, matching jnp.argmax)
        float bv = -1.0f; int bi = 0;
#pragma unroll
        for (int pr = 0; pr < 8; ++pr) {
            v2f dx = pk_add(px[pr], ncx);          // p + (-c) == p - c exactly
            v2f dy = pk_add(py[pr], ncy);
            v2f dz = pk_add(pz[pr], ncz);
            v2f s  = pk_add(pk_mul(dx, dx), pk_mul(dy, dy));
            v2f d2 = pk_add(s, pk_mul(dz, dz));    // ((dx^2+dy^2)+dz^2), exact order
            float m0 = fminf(mind[pr].x, d2.x);
            float m1 = fminf(mind[pr].y, d2.y);
            mind[pr].x = m0; mind[pr].y = m1;
            if (m0 > bv) { bv = m0; bi = (2 * pr + 0) * 256 + t; }
            if (m1 > bv) { bv = m1; bi = (2 * pr + 1) * 256 + t; }
        }

        // speculative coord gather for this lane's candidate; latency hides
        // under the DPP chain below
        float gx = lx[bi], gy = ly[bi], gz = lz[bi];

        // pack (d2 bits, ~idx): max key == (max d2, then min idx). d2 >= 0 so
        // float bits are order-isomorphic; keys are unique (idx unique).
        const u64 key0 = ((u64)__float_as_uint(bv) << 32) | (u32)(~bi);
        u64 key = wave_max_u64_dpp(key0);

        // broadcast wave winner from lane 63 (readlane ignores exec)
        u32 wlo = (u32)__builtin_amdgcn_readlane((int)(u32)key, 63);
        u32 whi = (u32)__builtin_amdgcn_readlane((int)(u32)(key >> 32), 63);
        u64 wkey = ((u64)whi << 32) | wlo;

        const int p = it & 1;
        if (key0 == wkey) {            // exactly one lane per wave
            mbox[p][wv].key = key0;
            mbox[p][wv].x = gx; mbox[p][wv].y = gy; mbox[p][wv].z = gz;
        }
        __syncthreads();

        u64 K0 = mbox[p][0].key, K1 = mbox[p][1].key;
        u64 K2 = mbox[p][2].key, K3 = mbox[p][3].key;
        float X0 = mbox[p][0].x, Y0 = mbox[p][0].y, Z0 = mbox[p][0].z;
        float X1 = mbox[p][1].x, Y1 = mbox[p][1].y, Z1 = mbox[p][1].z;
        float X2 = mbox[p][2].x, Y2 = mbox[p][2].y, Z2 = mbox[p][2].z;
        float X3 = mbox[p][3].x, Y3 = mbox[p][3].y, Z3 = mbox[p][3].z;

        bool c01 = K1 > K0;
        u64 Ka = c01 ? K1 : K0;
        float Xa = c01 ? X1 : X0, Ya = c01 ? Y1 : Y0, Za = c01 ? Z1 : Z0;
        bool c23 = K3 > K2;
        u64 Kb = c23 ? K3 : K2;
        float Xb = c23 ? X3 : X2, Yb = c23 ? Y3 : Y2, Zb = c23 ? Z3 : Z2;
        bool cab = Kb > Ka;
        u64 Kf = cab ? Kb : Ka;
        cx = cab ? Xb : Xa; cy = cab ? Yb : Ya; cz = cab ? Zb : Za;

        if (t == 0) {
            int pick = (int)(~(u32)Kf);
            sel[b * MPER + it] = b * NPTS + pick;
        }
    }
}

// ---------------- Kernel 2: ball query + K nearest (rank select) ----------------
__global__ __launch_bounds__(256) void ballq_kernel(
    const float* __restrict__ pos, const int* __restrict__ sel,
    int* __restrict__ nbr, int* __restrict__ cnt,
    float* __restrict__ out_pos, float* __restrict__ out_batch)
{
    __shared__ float cd[4][CAP];
    __shared__ int   ci[4][CAP];

    const int wv   = threadIdx.x >> 6;
    const int lane = threadIdx.x & 63;
    const int c    = blockIdx.x * 4 + wv;
    const int sg   = sel[c];
    const int b    = c >> 10;            // c / MPER
    const int base = b * NPTS;
    const float* pb = pos + (size_t)base * 3;
    const float qx = pos[(size_t)sg * 3 + 0];
    const float qy = pos[(size_t)sg * 3 + 1];
    const float qz = pos[(size_t)sg * 3 + 2];

    int n = 0;
    for (int r0 = 0; r0 < NPTS; r0 += 64) {
        const int j = r0 + lane;
        float x = pb[j * 3 + 0], y = pb[j * 3 + 1], z = pb[j * 3 + 2];
        float d2 = d2f(x, y, z, qx, qy, qz);
        bool inside = ((double)d2 <= R2D);
        unsigned long long m = __ballot(inside);
        if (inside) {
            int myoff = n + __popcll(m & ((1ull << lane) - 1ull));
            if (myoff < CAP) { cd[wv][myoff] = d2; ci[wv][myoff] = j; }
        }
        n += __popcll(m);
    }
    n = min(n, CAP);
    __syncthreads();

    for (int i = lane; i < n; i += 64) {
        float d = cd[wv][i]; int id = ci[wv][i];
        int rank = 0;
        for (int j = 0; j < n; ++j) {
            float dj = cd[wv][j]; int ij = ci[wv][j];
            rank += (dj < d || (dj == d && ij < id)) ? 1 : 0;
        }
        if (rank < KNN) nbr[(size_t)c * KNN + rank] = base + id;
    }
    if (lane == 0) {
        cnt[c] = min(n, KNN);
        out_pos[c * 3 + 0] = qx;
        out_pos[c * 3 + 1] = qy;
        out_pos[c * 3 + 2] = qz;
        out_batch[c] = (float)b;
    }
}

// ---------------- weight prep: bf16 transposed+padded weights into ws ----------
// ws layout (ushort units): W1t[64][104] | W2t[64][72] | W3t[128][72]
#define W1T_U 6656
#define W2T_U 4608
#define W3T_U 9216
#define WTOT_U 20480

__global__ __launch_bounds__(256) void prep_weights(
    const float* __restrict__ W1, const float* __restrict__ W2,
    const float* __restrict__ W3, unsigned short* __restrict__ wsW)
{
    int i = blockIdx.x * 256 + threadIdx.x;
    if (i >= WTOT_U) return;
    float v;
    if (i < W1T_U) {
        int cr = i / 104, k = i - cr * 104;
        v = (k < 67) ? W1[k * 64 + cr] : 0.0f;
    } else if (i < W1T_U + W2T_U) {
        int j = i - W1T_U;
        int cr = j / 72, k = j - cr * 72;
        v = (k < 64) ? W2[k * 64 + cr] : 0.0f;
    } else {
        int j = i - (W1T_U + W2T_U);
        int cr = j / 72, k = j - cr * 72;
        v = (k < 64) ? W3[k * 128 + cr] : 0.0f;
    }
    wsW[i] = f2bf(v);
}

// ---------------- Kernel 3: gather + MFMA MLP + masked max ---------------------
__global__ __launch_bounds__(256) void mlp_kernel(
    const float* __restrict__ x, const float* __restrict__ pos,
    const int* __restrict__ nbr, const int* __restrict__ cnt,
    const float* __restrict__ out_pos,
    const unsigned short* __restrict__ wsW,
    const float* __restrict__ b1, const float* __restrict__ b2,
    const float* __restrict__ b3,
    float* __restrict__ out_x)
{
    __shared__ __align__(16) unsigned short smA[6656];   // A1[64][104]; later H2[64][72]; later f32 partial[4][128]
    __shared__ __align__(16) unsigned short smW[WTOT_U]; // W1t (later H1[64][72]) | W2t | W3t

    const int c = blockIdx.x;
    const int t = threadIdx.x;
    const int n = cnt[c];

    // ---- stage weights ws -> LDS (linear, 40960 B) ----
    {
        const uint4* src = (const uint4*)wsW;
        uint4* dst = (uint4*)smW;
#pragma unroll
        for (int i = 0; i < 10; ++i) dst[t + 256 * i] = src[t + 256 * i];
    }

    // ---- stage A1: row k = [bf16(x[nb][0..64)), bf16(pos[nb]-q), zeros] ----
    {
        const int k = t >> 2, g = t & 3;
        const bool valid = k < n;
        const int nb = valid ? nbr[(size_t)c * KNN + k] : 0;
        const float* xr = x + (size_t)nb * CIN + g * 16;
        float4 f0, f1, f2, f3;
        if (valid) {
            f0 = *(const float4*)(xr + 0);
            f1 = *(const float4*)(xr + 4);
            f2 = *(const float4*)(xr + 8);
            f3 = *(const float4*)(xr + 12);
        } else {
            f0 = float4{0.f, 0.f, 0.f, 0.f};
            f1 = f0; f2 = f0; f3 = f0;
        }
        uint4 ua = { pk2(f0.x, f0.y), pk2(f0.z, f0.w), pk2(f1.x, f1.y), pk2(f1.z, f1.w) };
        uint4 ub = { pk2(f2.x, f2.y), pk2(f2.z, f2.w), pk2(f3.x, f3.y), pk2(f3.z, f3.w) };
        *(uint4*)&smA[k * 104 + g * 16 + 0] = ua;
        *(uint4*)&smA[k * 104 + g * 16 + 8] = ub;
        if (g == 0) {
            float r0 = 0.f, r1 = 0.f, r2 = 0.f;
            if (valid) {
                float q0 = out_pos[c * 3 + 0];
                float q1 = out_pos[c * 3 + 1];
                float q2 = out_pos[c * 3 + 2];
                r0 = __fsub_rn(pos[(size_t)nb * 3 + 0], q0);
                r1 = __fsub_rn(pos[(size_t)nb * 3 + 1], q1);
                r2 = __fsub_rn(pos[(size_t)nb * 3 + 2], q2);
            }
            uint4 uz = { 0u, 0u, 0u, 0u };
            uint4 ur = { pk2(r0, r1), (u32)f2bf(r2), 0u, 0u };
            *(uint4*)&smA[k * 104 + 64] = ur;
            *(uint4*)&smA[k * 104 + 72] = uz;
            *(uint4*)&smA[k * 104 + 80] = uz;
            *(uint4*)&smA[k * 104 + 88] = uz;
            *(uint4*)&smA[k * 104 + 96] = uz;
        }
    }
    __syncthreads();

    const int l  = t & 63;
    const int w  = t >> 6;
    const int lr = l & 15;
    const int kg = l >> 4;

    float bias1[4], bias2[4];
#pragma unroll
    for (int nt = 0; nt < 4; ++nt) {
        bias1[nt] = b1[nt * 16 + lr];
        bias2[nt] = b2[nt * 16 + lr];
    }

    const unsigned short* W1t = smW;                    // stride 104
    const unsigned short* W2t = smW + W1T_U;            // stride 72
    const unsigned short* W3t = smW + W1T_U + W2T_U;    // stride 72
    unsigned short* H1 = smW;                           // [64][72] overlays W1t
    unsigned short* H2 = smA;                           // [64][72] overlays A1

    // ---- layer 1: A1[64][96+] x W1t -> H1 (relu) ----
    f32x4 acc1[4];
#pragma unroll
    for (int nt = 0; nt < 4; ++nt) acc1[nt] = f32x4{0.f, 0.f, 0.f, 0.f};
    {
        const int ao = (w * 16 + lr) * 104 + kg * 8;
        const int bo = lr * 104 + kg * 8;
#pragma unroll
        for (int kc = 0; kc < 3; ++kc) {
            s16x8 af = *(const s16x8*)&smA[ao + kc * 32];
#pragma unroll
            for (int nt = 0; nt < 4; ++nt) {
                s16x8 bf = *(const s16x8*)&W1t[bo + nt * 1664 + kc * 32];
                acc1[nt] = mfma16(af, bf, acc1[nt]);
            }
        }
    }
    __syncthreads();   // all W1t/A1 reads complete before overlaying W1t with H1
#pragma unroll
    for (int nt = 0; nt < 4; ++nt) {
        const int col = nt * 16 + lr;
#pragma unroll
        for (int r = 0; r < 4; ++r) {
            const int row = w * 16 + kg * 4 + r;
            float v = fmaxf(acc1[nt][r] + bias1[nt], 0.0f);
            H1[row * 72 + col] = f2bf(v);
        }
    }
    __syncthreads();

    // ---- layer 2: H1 x W2t -> H2 (relu) ----
    f32x4 acc2[4];
#pragma unroll
    for (int nt = 0; nt < 4; ++nt) acc2[nt] = f32x4{0.f, 0.f, 0.f, 0.f};
    {
        const int ao = (w * 16 + lr) * 72 + kg * 8;
        const int bo = lr * 72 + kg * 8;
#pragma unroll
        for (int kc = 0; kc < 2; ++kc) {
            s16x8 af = *(const s16x8*)&H1[ao + kc * 32];
#pragma unroll
            for (int nt = 0; nt < 4; ++nt) {
                s16x8 bf = *(const s16x8*)&W2t[bo + nt * 1152 + kc * 32];
                acc2[nt] = mfma16(af, bf, acc2[nt]);
            }
        }
    }
    // H2 overlays A1 (dead since layer-1 barrier); disjoint from H1/W2t.
#pragma unroll
    for (int nt = 0; nt < 4; ++nt) {
        const int col = nt * 16 + lr;
#pragma unroll
        for (int r = 0; r < 4; ++r) {
            const int row = w * 16 + kg * 4 + r;
            float v = fmaxf(acc2[nt][r] + bias2[nt], 0.0f);
            H2[row * 72 + col] = f2bf(v);
        }
    }
    __syncthreads();

    // ---- layer 3: H2 x W3t -> acc3 (64x128 per block) ----
    f32x4 acc3[8];
#pragma unroll
    for (int nt = 0; nt < 8; ++nt) acc3[nt] = f32x4{0.f, 0.f, 0.f, 0.f};
    {
        const int ao = (w * 16 + lr) * 72 + kg * 8;
        const int bo = lr * 72 + kg * 8;
#pragma unroll
        for (int kc = 0; kc < 2; ++kc) {
            s16x8 af = *(const s16x8*)&H2[ao + kc * 32];
#pragma unroll
            for (int nt = 0; nt < 8; ++nt) {
                s16x8 bf = *(const s16x8*)&W3t[bo + nt * 1152 + kc * 32];
                acc3[nt] = mfma16(af, bf, acc3[nt]);
            }
        }
    }

    // ---- masked max over valid rows; bias added after max (column-constant) ----
    float pm[8];
#pragma unroll
    for (int nt = 0; nt < 8; ++nt) pm[nt] = -1e30f;
#pragma unroll
    for (int r = 0; r < 4; ++r) {
        const int row = w * 16 + kg * 4 + r;
        if (row < n) {
#pragma unroll
            for (int nt = 0; nt < 8; ++nt) pm[nt] = fmaxf(pm[nt], acc3[nt][r]);
        }
    }
#pragma unroll
    for (int nt = 0; nt < 8; ++nt) {
        pm[nt] = fmaxf(pm[nt], __shfl_xor(pm[nt], 16));
        pm[nt] = fmaxf(pm[nt], __shfl_xor(pm[nt], 32));
    }
    __syncthreads();   // all layer-3 LDS reads done; reuse smA as f32 partials
    float* pbuf = (float*)smA;            // [4][128]
    if (kg == 0) {
#pragma unroll
        for (int nt = 0; nt < 8; ++nt) pbuf[w * 128 + nt * 16 + lr] = pm[nt];
    }
    __syncthreads();
    if (t < 128) {
        float m = fmaxf(fmaxf(pbuf[t], pbuf[128 + t]),
                        fmaxf(pbuf[256 + t], pbuf[384 + t]));
        out_x[(size_t)c * 128 + t] = m + b3[t];
    }
}

extern "C" void kernel_launch(void* const* d_in, const int* in_sizes, int n_in,
                              void* d_out, int out_size, void* d_ws, size_t ws_size,
                              hipStream_t stream)
{
    const float* x   = (const float*)d_in[0];
    const float* pos = (const float*)d_in[1];
    const float* W1 = (const float*)d_in[3];
    const float* b1 = (const float*)d_in[4];
    const float* W2 = (const float*)d_in[5];
    const float* b2 = (const float*)d_in[6];
    const float* W3 = (const float*)d_in[7];
    const float* b3 = (const float*)d_in[8];

    float* out_x     = (float*)d_out;                    // [8192,128]
    float* out_pos   = out_x + (size_t)MTOT * 128;       // [8192,3]
    float* out_batch = out_pos + (size_t)MTOT * 3;       // [8192]

    int* sel = (int*)d_ws;                               // [8192]
    int* nbr = sel + MTOT;                               // [8192*64]
    int* cnt = nbr + (size_t)MTOT * KNN;                 // [8192]
    unsigned short* wsW = (unsigned short*)(cnt + MTOT); // [20480] bf16 weights

    prep_weights<<<(WTOT_U + 255) / 256, 256, 0, stream>>>(W1, W2, W3, wsW);
    fps_kernel<<<NB, 256, 0, stream>>>(pos, sel);
    ballq_kernel<<<MTOT / 4, 256, 0, stream>>>(pos, sel, nbr, cnt, out_pos, out_batch);
    mlp_kernel<<<MTOT, 256, 0, stream>>>(x, pos, nbr, cnt, out_pos, wsW,
                                         b1, b2, b3, out_x);
}

// Round 7
// 740.377 us; speedup vs baseline: 1.3094x; 1.2076x over previous
//
#include <hip/hip_runtime.h>
#include <math.h>

#define NB   8
#define NPTS 4096
#define MPER 1024
#define MTOT (NB*MPER)
#define CIN  64
#define KNN  64
#define CAP  512
// (0.2*0.2) computed in double, as the reference's python-float R*R
#define R2D  0.04000000000000001

typedef unsigned int u32;
typedef unsigned long long u64;
typedef float v2f __attribute__((ext_vector_type(2)));
using s16x8 = __attribute__((ext_vector_type(8))) short;   // 8 bf16 (4 VGPRs)
using f32x4 = __attribute__((ext_vector_type(4))) float;

// exact IEEE fp32 distance, reference order: ((dx*dx + dy*dy) + dz*dz), no FMA
__device__ __forceinline__ float d2f(float ax, float ay, float az,
                                     float bx, float by, float bz) {
    float dx = __fsub_rn(ax, bx);
    float dy = __fsub_rn(ay, by);
    float dz = __fsub_rn(az, bz);
    return __fadd_rn(__fadd_rn(__fmul_rn(dx, dx), __fmul_rn(dy, dy)),
                     __fmul_rn(dz, dz));
}

// CDNA packed 2xFP32 ops — IEEE-identical per component; asm, never contracted.
// (bit-exactness HW-verified in rounds 3/5/6: FPS picks matched reference)
__device__ __forceinline__ v2f pk_add(v2f a, v2f b) {
    v2f d;
    asm("v_pk_add_f32 %0, %1, %2" : "=v"(d) : "v"(a), "v"(b));
    return d;
}
__device__ __forceinline__ v2f pk_mul(v2f a, v2f b) {
    v2f d;
    asm("v_pk_mul_f32 %0, %1, %2" : "=v"(d) : "v"(a), "v"(b));
    return d;
}

// float -> bf16 bits, round-to-nearest-even (finite inputs only)
__device__ __forceinline__ unsigned short f2bf(float f) {
    u32 x = __float_as_uint(f);
    u32 r = (x + 0x7fffu + ((x >> 16) & 1u)) >> 16;
    return (unsigned short)r;
}
__device__ __forceinline__ u32 pk2(float a, float b) {
    return (u32)f2bf(a) | ((u32)f2bf(b) << 16);
}

__device__ __forceinline__ f32x4 mfma16(s16x8 a, s16x8 b, f32x4 c) {
    return __builtin_amdgcn_mfma_f32_16x16x32_bf16(a, b, c, 0, 0, 0);
}

// full-wave (64-lane) max reduction of a u64 key via DPP; result valid in lane 63.
__device__ __forceinline__ u64 wave_max_u64_dpp(u64 key)
{
#define DPPMAX(ctrl, rmask) do {                                                   \
        u32 lo_ = (u32)key;                                                        \
        u32 hi_ = (u32)(key >> 32);                                                \
        u32 plo = (u32)__builtin_amdgcn_update_dpp(                                \
            0, (int)lo_, ctrl, rmask, 0xf, false);                                 \
        u32 phi = (u32)__builtin_amdgcn_update_dpp(                                \
            0, (int)hi_, ctrl, rmask, 0xf, false);                                 \
        u64 pk = ((u64)phi << 32) | plo;                                           \
        if (pk > key) key = pk;                                                    \
    } while (0)
    DPPMAX(0x111, 0xf);   // row_shr:1
    DPPMAX(0x112, 0xf);   // row_shr:2
    DPPMAX(0x114, 0xf);   // row_shr:4
    DPPMAX(0x118, 0xf);   // row_shr:8
    DPPMAX(0x142, 0xa);   // row_bcast:15 -> rows 1,3
    DPPMAX(0x143, 0xc);   // row_bcast:31 -> rows 2,3
#undef DPPMAX
    return key;
}

// ---------------- Kernel 1: farthest point sampling ----------------
// round-2 structure (616us baseline) with exactly two deltas:
//   (a) pk-packed 2xFP32 distance/min phase (bit-exact, HW-verified)
//   (b) coords interleaved as float4 -> single ds_read_b128 broadcast fetch
// Per iteration: pk phase A + local argmax -> u64 DPP wave argmax -> lane63
// key to LDS -> s_barrier -> 4-way select -> one b128 coord broadcast.
__global__ __launch_bounds__(256) void fps_kernel(const float* __restrict__ pos,
                                                  int* __restrict__ sel)
{
    const int b    = blockIdx.x;
    const int t    = threadIdx.x;
    const int lane = t & 63;
    const int wv   = t >> 6;
    const float* pb = pos + (size_t)b * NPTS * 3;

    __shared__ float4 lp[NPTS];          // interleaved coords (64 KB)
    __shared__ u64 part[2][4];

    v2f px[8], py[8], pz[8], mind[8];
#pragma unroll
    for (int pr = 0; pr < 8; ++pr) {
        int j0 = (2 * pr + 0) * 256 + t;
        int j1 = (2 * pr + 1) * 256 + t;
        float x0 = pb[j0 * 3 + 0], y0 = pb[j0 * 3 + 1], z0 = pb[j0 * 3 + 2];
        float x1 = pb[j1 * 3 + 0], y1 = pb[j1 * 3 + 1], z1 = pb[j1 * 3 + 2];
        px[pr] = v2f{x0, x1}; py[pr] = v2f{y0, y1}; pz[pr] = v2f{z0, z1};
        mind[pr] = v2f{3.0e38f, 3.0e38f};   // first fmin yields exactly d2-to-p0
        lp[j0] = float4{x0, y0, z0, 0.f};
        lp[j1] = float4{x1, y1, z1, 0.f};
    }
    if (t == 0) sel[b * MPER + 0] = b * NPTS + 0;
    __syncthreads();

    float4 c0 = lp[0];
    float cx = c0.x, cy = c0.y, cz = c0.z;

    for (int it = 1; it < MPER; ++it) {
        const v2f ncx = v2f{-cx, -cx};
        const v2f ncy = v2f{-cy, -cy};
        const v2f ncz = v2f{-cz, -cz};

        // local argmax of updated min-dists (ascending j + strict > keeps the
        // lowest index on ties, matching jnp.argmax)
        float bv = -1.0f; int bi = 0;
#pragma unroll
        for (int pr = 0; pr < 8; ++pr) {
            v2f dx = pk_add(px[pr], ncx);          // p + (-c) == p - c exactly
            v2f dy = pk_add(py[pr], ncy);
            v2f dz = pk_add(pz[pr], ncz);
            v2f s  = pk_add(pk_mul(dx, dx), pk_mul(dy, dy));
            v2f d2 = pk_add(s, pk_mul(dz, dz));    // ((dx^2+dy^2)+dz^2), exact order
            float m0 = fminf(mind[pr].x, d2.x);
            float m1 = fminf(mind[pr].y, d2.y);
            mind[pr].x = m0; mind[pr].y = m1;
            if (m0 > bv) { bv = m0; bi = (2 * pr + 0) * 256 + t; }
            if (m1 > bv) { bv = m1; bi = (2 * pr + 1) * 256 + t; }
        }

        // pack (d2 bits, ~idx): max key == (max d2, then min idx). d2 >= 0 so
        // float bits are order-isomorphic.
        u64 key = ((u64)__float_as_uint(bv) << 32) | (u32)(~bi);
        key = wave_max_u64_dpp(key);

        const int p = it & 1;
        if (lane == 63) part[p][wv] = key;
        __syncthreads();

        u64 k0 = part[p][0];
        u64 k1 = part[p][1];
        u64 k2 = part[p][2];
        u64 k3 = part[p][3];
        u64 ka = k0 > k1 ? k0 : k1;
        u64 kb = k2 > k3 ? k2 : k3;
        u64 km = ka > kb ? ka : kb;
        int pick = (int)(~(u32)km);

        float4 cc = lp[pick];            // single b128 broadcast
        cx = cc.x; cy = cc.y; cz = cc.z;
        if (t == 0) sel[b * MPER + it] = b * NPTS + pick;
    }
}

// ---------------- Kernel 2: ball query + K nearest (rank select) ----------------
__global__ __launch_bounds__(256) void ballq_kernel(
    const float* __restrict__ pos, const int* __restrict__ sel,
    int* __restrict__ nbr, int* __restrict__ cnt,
    float* __restrict__ out_pos, float* __restrict__ out_batch)
{
    __shared__ float cd[4][CAP];
    __shared__ int   ci[4][CAP];

    const int wv   = threadIdx.x >> 6;
    const int lane = threadIdx.x & 63;
    const int c    = blockIdx.x * 4 + wv;
    const int sg   = sel[c];
    const int b    = c >> 10;            // c / MPER
    const int base = b * NPTS;
    const float* pb = pos + (size_t)base * 3;
    const float qx = pos[(size_t)sg * 3 + 0];
    const float qy = pos[(size_t)sg * 3 + 1];
    const float qz = pos[(size_t)sg * 3 + 2];

    int n = 0;
    for (int r0 = 0; r0 < NPTS; r0 += 64) {
        const int j = r0 + lane;
        float x = pb[j * 3 + 0], y = pb[j * 3 + 1], z = pb[j * 3 + 2];
        float d2 = d2f(x, y, z, qx, qy, qz);
        bool inside = ((double)d2 <= R2D);
        unsigned long long m = __ballot(inside);
        if (inside) {
            int myoff = n + __popcll(m & ((1ull << lane) - 1ull));
            if (myoff < CAP) { cd[wv][myoff] = d2; ci[wv][myoff] = j; }
        }
        n += __popcll(m);
    }
    n = min(n, CAP);
    __syncthreads();

    for (int i = lane; i < n; i += 64) {
        float d = cd[wv][i]; int id = ci[wv][i];
        int rank = 0;
        for (int j = 0; j < n; ++j) {
            float dj = cd[wv][j]; int ij = ci[wv][j];
            rank += (dj < d || (dj == d && ij < id)) ? 1 : 0;
        }
        if (rank < KNN) nbr[(size_t)c * KNN + rank] = base + id;
    }
    if (lane == 0) {
        cnt[c] = min(n, KNN);
        out_pos[c * 3 + 0] = qx;
        out_pos[c * 3 + 1] = qy;
        out_pos[c * 3 + 2] = qz;
        out_batch[c] = (float)b;
    }
}

// ---------------- weight prep: bf16 transposed+padded weights into ws ----------
// ws layout (ushort units): W1t[64][104] | W2t[64][72] | W3t[128][72]
#define W1T_U 6656
#define W2T_U 4608
#define W3T_U 9216
#define WTOT_U 20480

__global__ __launch_bounds__(256) void prep_weights(
    const float* __restrict__ W1, const float* __restrict__ W2,
    const float* __restrict__ W3, unsigned short* __restrict__ wsW)
{
    int i = blockIdx.x * 256 + threadIdx.x;
    if (i >= WTOT_U) return;
    float v;
    if (i < W1T_U) {
        int cr = i / 104, k = i - cr * 104;
        v = (k < 67) ? W1[k * 64 + cr] : 0.0f;
    } else if (i < W1T_U + W2T_U) {
        int j = i - W1T_U;
        int cr = j / 72, k = j - cr * 72;
        v = (k < 64) ? W2[k * 64 + cr] : 0.0f;
    } else {
        int j = i - (W1T_U + W2T_U);
        int cr = j / 72, k = j - cr * 72;
        v = (k < 64) ? W3[k * 128 + cr] : 0.0f;
    }
    wsW[i] = f2bf(v);
}

// ---------------- Kernel 3: gather + MFMA MLP + masked max ---------------------
__global__ __launch_bounds__(256) void mlp_kernel(
    const float* __restrict__ x, const float* __restrict__ pos,
    const int* __restrict__ nbr, const int* __restrict__ cnt,
    const float* __restrict__ out_pos,
    const unsigned short* __restrict__ wsW,
    const float* __restrict__ b1, const float* __restrict__ b2,
    const float* __restrict__ b3,
    float* __restrict__ out_x)
{
    __shared__ __align__(16) unsigned short smA[6656];   // A1[64][104]; later H2[64][72]; later f32 partial[4][128]
    __shared__ __align__(16) unsigned short smW[WTOT_U]; // W1t (later H1[64][72]) | W2t | W3t

    const int c = blockIdx.x;
    const int t = threadIdx.x;
    const int n = cnt[c];

    // ---- stage weights ws -> LDS (linear, 40960 B) ----
    {
        const uint4* src = (const uint4*)wsW;
        uint4* dst = (uint4*)smW;
#pragma unroll
        for (int i = 0; i < 10; ++i) dst[t + 256 * i] = src[t + 256 * i];
    }

    // ---- stage A1: row k = [bf16(x[nb][0..64)), bf16(pos[nb]-q), zeros] ----
    {
        const int k = t >> 2, g = t & 3;
        const bool valid = k < n;
        const int nb = valid ? nbr[(size_t)c * KNN + k] : 0;
        const float* xr = x + (size_t)nb * CIN + g * 16;
        float4 f0, f1, f2, f3;
        if (valid) {
            f0 = *(const float4*)(xr + 0);
            f1 = *(const float4*)(xr + 4);
            f2 = *(const float4*)(xr + 8);
            f3 = *(const float4*)(xr + 12);
        } else {
            f0 = float4{0.f, 0.f, 0.f, 0.f};
            f1 = f0; f2 = f0; f3 = f0;
        }
        uint4 ua = { pk2(f0.x, f0.y), pk2(f0.z, f0.w), pk2(f1.x, f1.y), pk2(f1.z, f1.w) };
        uint4 ub = { pk2(f2.x, f2.y), pk2(f2.z, f2.w), pk2(f3.x, f3.y), pk2(f3.z, f3.w) };
        *(uint4*)&smA[k * 104 + g * 16 + 0] = ua;
        *(uint4*)&smA[k * 104 + g * 16 + 8] = ub;
        if (g == 0) {
            float r0 = 0.f, r1 = 0.f, r2 = 0.f;
            if (valid) {
                float q0 = out_pos[c * 3 + 0];
                float q1 = out_pos[c * 3 + 1];
                float q2 = out_pos[c * 3 + 2];
                r0 = __fsub_rn(pos[(size_t)nb * 3 + 0], q0);
                r1 = __fsub_rn(pos[(size_t)nb * 3 + 1], q1);
                r2 = __fsub_rn(pos[(size_t)nb * 3 + 2], q2);
            }
            uint4 uz = { 0u, 0u, 0u, 0u };
            uint4 ur = { pk2(r0, r1), (u32)f2bf(r2), 0u, 0u };
            *(uint4*)&smA[k * 104 + 64] = ur;
            *(uint4*)&smA[k * 104 + 72] = uz;
            *(uint4*)&smA[k * 104 + 80] = uz;
            *(uint4*)&smA[k * 104 + 88] = uz;
            *(uint4*)&smA[k * 104 + 96] = uz;
        }
    }
    __syncthreads();

    const int l  = t & 63;
    const int w  = t >> 6;
    const int lr = l & 15;
    const int kg = l >> 4;

    float bias1[4], bias2[4];
#pragma unroll
    for (int nt = 0; nt < 4; ++nt) {
        bias1[nt] = b1[nt * 16 + lr];
        bias2[nt] = b2[nt * 16 + lr];
    }

    const unsigned short* W1t = smW;                    // stride 104
    const unsigned short* W2t = smW + W1T_U;            // stride 72
    const unsigned short* W3t = smW + W1T_U + W2T_U;    // stride 72
    unsigned short* H1 = smW;                           // [64][72] overlays W1t
    unsigned short* H2 = smA;                           // [64][72] overlays A1

    // ---- layer 1: A1[64][96+] x W1t -> H1 (relu) ----
    f32x4 acc1[4];
#pragma unroll
    for (int nt = 0; nt < 4; ++nt) acc1[nt] = f32x4{0.f, 0.f, 0.f, 0.f};
    {
        const int ao = (w * 16 + lr) * 104 + kg * 8;
        const int bo = lr * 104 + kg * 8;
#pragma unroll
        for (int kc = 0; kc < 3; ++kc) {
            s16x8 af = *(const s16x8*)&smA[ao + kc * 32];
#pragma unroll
            for (int nt = 0; nt < 4; ++nt) {
                s16x8 bf = *(const s16x8*)&W1t[bo + nt * 1664 + kc * 32];
                acc1[nt] = mfma16(af, bf, acc1[nt]);
            }
        }
    }
    __syncthreads();   // all W1t/A1 reads complete before overlaying W1t with H1
#pragma unroll
    for (int nt = 0; nt < 4; ++nt) {
        const int col = nt * 16 + lr;
#pragma unroll
        for (int r = 0; r < 4; ++r) {
            const int row = w * 16 + kg * 4 + r;
            float v = fmaxf(acc1[nt][r] + bias1[nt], 0.0f);
            H1[row * 72 + col] = f2bf(v);
        }
    }
    __syncthreads();

    // ---- layer 2: H1 x W2t -> H2 (relu) ----
    f32x4 acc2[4];
#pragma unroll
    for (int nt = 0; nt < 4; ++nt) acc2[nt] = f32x4{0.f, 0.f, 0.f, 0.f};
    {
        const int ao = (w * 16 + lr) * 72 + kg * 8;
        const int bo = lr * 72 + kg * 8;
#pragma unroll
        for (int kc = 0; kc < 2; ++kc) {
            s16x8 af = *(const s16x8*)&H1[ao + kc * 32];
#pragma unroll
            for (int nt = 0; nt < 4; ++nt) {
                s16x8 bf = *(const s16x8*)&W2t[bo + nt * 1152 + kc * 32];
                acc2[nt] = mfma16(af, bf, acc2[nt]);
            }
        }
    }
    // H2 overlays A1 (dead since layer-1 barrier); disjoint from H1/W2t.
#pragma unroll
    for (int nt = 0; nt < 4; ++nt) {
        const int col = nt * 16 + lr;
#pragma unroll
        for (int r = 0; r < 4; ++r) {
            const int row = w * 16 + kg * 4 + r;
            float v = fmaxf(acc2[nt][r] + bias2[nt], 0.0f);
            H2[row * 72 + col] = f2bf(v);
        }
    }
    __syncthreads();

    // ---- layer 3: H2 x W3t -> acc3 (64x128 per block) ----
    f32x4 acc3[8];
#pragma unroll
    for (int nt = 0; nt < 8; ++nt) acc3[nt] = f32x4{0.f, 0.f, 0.f, 0.f};
    {
        const int ao = (w * 16 + lr) * 72 + kg * 8;
        const int bo = lr * 72 + kg * 8;
#pragma unroll
        for (int kc = 0; kc < 2; ++kc) {
            s16x8 af = *(const s16x8*)&H2[ao + kc * 32];
#pragma unroll
            for (int nt = 0; nt < 8; ++nt) {
                s16x8 bf = *(const s16x8*)&W3t[bo + nt * 1152 + kc * 32];
                acc3[nt] = mfma16(af, bf, acc3[nt]);
            }
        }
    }

    // ---- masked max over valid rows; bias added after max (column-constant) ----
    float pm[8];
#pragma unroll
    for (int nt = 0; nt < 8; ++nt) pm[nt] = -1e30f;
#pragma unroll
    for (int r = 0; r < 4; ++r) {
        const int row = w * 16 + kg * 4 + r;
        if (row < n) {
#pragma unroll
            for (int nt = 0; nt < 8; ++nt) pm[nt] = fmaxf(pm[nt], acc3[nt][r]);
        }
    }
#pragma unroll
    for (int nt = 0; nt < 8; ++nt) {
        pm[nt] = fmaxf(pm[nt], __shfl_xor(pm[nt], 16));
        pm[nt] = fmaxf(pm[nt], __shfl_xor(pm[nt], 32));
    }
    __syncthreads();   // all layer-3 LDS reads done; reuse smA as f32 partials
    float* pbuf = (float*)smA;            // [4][128]
    if (kg == 0) {
#pragma unroll
        for (int nt = 0; nt < 8; ++nt) pbuf[w * 128 + nt * 16 + lr] = pm[nt];
    }
    __syncthreads();
    if (t < 128) {
        float m = fmaxf(fmaxf(pbuf[t], pbuf[128 + t]),
                        fmaxf(pbuf[256 + t], pbuf[384 + t]));
        out_x[(size_t)c * 128 + t] = m + b3[t];
    }
}

extern "C" void kernel_launch(void* const* d_in, const int* in_sizes, int n_in,
                              void* d_out, int out_size, void* d_ws, size_t ws_size,
                              hipStream_t stream)
{
    const float* x   = (const float*)d_in[0];
    const float* pos = (const float*)d_in[1];
    const float* W1 = (const float*)d_in[3];
    const float* b1 = (const float*)d_in[4];
    const float* W2 = (const float*)d_in[5];
    const float* b2 = (const float*)d_in[6];
    const float* W3 = (const float*)d_in[7];
    const float* b3 = (const float*)d_in[8];

    float* out_x     = (float*)d_out;                    // [8192,128]
    float* out_pos   = out_x + (size_t)MTOT * 128;       // [8192,3]
    float* out_batch = out_pos + (size_t)MTOT * 3;       // [8192]

    int* sel = (int*)d_ws;                               // [8192]
    int* nbr = sel + MTOT;                               // [8192*64]
    int* cnt = nbr + (size_t)MTOT * KNN;                 // [8192]
    unsigned short* wsW = (unsigned short*)(cnt + MTOT); // [20480] bf16 weights

    prep_weights<<<(WTOT_U + 255) / 256, 256, 0, stream>>>(W1, W2, W3, wsW);
    fps_kernel<<<NB, 256, 0, stream>>>(pos, sel);
    ballq_kernel<<<MTOT / 4, 256, 0, stream>>>(pos, sel, nbr, cnt, out_pos, out_batch);
    mlp_kernel<<<MTOT, 256, 0, stream>>>(x, pos, nbr, cnt, out_pos, wsW,
                                         b1, b2, b3, out_x);
}